// Round 4
// baseline (830.429 us; speedup 1.0000x reference)
//
#include <hip/hip_runtime.h>
#include <math.h>

#define NEGV -1e30f
#define LOG2E 1.44269504088896f
#define LN2   0.69314718055995f

constexpr int SSTRIDE = 264;   // padded extended-state stride (S=257 max), floats

// Gather: em[(b*T+t)*SSTRIDE + s] = log2e * lp[b,t,ext[s]] (fp32), NEGV if state invalid.
// One wave per (b,t) row: stream 4KB row coalesced -> LDS, gather from LDS.
__global__ __launch_bounds__(256) void gather_kernel(
    const float* __restrict__ lp, const int* __restrict__ targets,
    const int* __restrict__ ilen, const int* __restrict__ tlen,
    float* __restrict__ em, int B, int T, int C, int L) {
  __shared__ float rowbuf[4][1024];
  const int wave = threadIdx.x >> 6;
  const int lane = threadIdx.x & 63;
  const int row = blockIdx.x * 4 + wave;
  if (row >= B * T) return;
  const int b = row / T;
  const int t = row - b * T;
  if (t >= ilen[b]) return;                    // never read by DP
  const int tl = tlen[b];
  const int* tg = targets + (size_t)b * L;

  const float4* src = (const float4*)(lp + (size_t)row * C);
  float4* dstl = (float4*)rowbuf[wave];
#pragma unroll
  for (int k = 0; k < 4; ++k) dstl[lane + 64 * k] = src[lane + 64 * k];
  asm volatile("s_waitcnt lgkmcnt(0)" ::: "memory");  // wave-synchronous LDS visibility

  const float* rb = rowbuf[wave];
  float* dst = em + (size_t)row * SSTRIDE;
  const float blank2 = rb[0] * LOG2E;
#pragma unroll
  for (int k = 0; k < 5; ++k) {
    int s = lane + 64 * k;                     // 0..319, write 0..263
    if (s >= SSTRIDE) break;
    float v;
    if (s & 1) {
      int li = (s - 1) >> 1;                   // <= 131
      v = (li < tl && li < L) ? rb[tg[li]] * LOG2E : NEGV;
    } else {
      v = ((s >> 1) <= tl) ? blank2 : NEGV;
    }
    dst[s] = v;
  }
}

// DP: one block (256 threads = 4 waves) per batch element; thread i owns state i,
// thread 255 additionally owns state 256 (even/blank: 2-way recursion, both inputs
// already in thread 255's registers). Neighbor alpha[s-1], alpha[s-2] via
// double-buffered LDS array (stride-1 reads: conflict-free), 1 barrier/step.
__global__ __launch_bounds__(256) void ctc_dp_kernel(
    const float* __restrict__ em, const int* __restrict__ targets,
    const int* __restrict__ ilen, const int* __restrict__ tlen,
    float* __restrict__ out, int T, int L) {
  const int b = blockIdx.x;
  const int s = threadIdx.x;                   // state 0..255
  const int len = ilen[b];
  const int tl = tlen[b];
  const int Sb = 2 * tl + 1;
  const int* tg = targets + (size_t)b * L;
  const float* base = em + (size_t)b * T * SSTRIDE;
  const bool last = (s == 255);

  bool sk = false;
  if ((s & 1) && s >= 3 && s < Sb) {
    int li = (s - 1) >> 1;
    sk = (tg[li] != tg[li - 1]);
  }
  const bool valid  = s < Sb;
  const bool valid2 = 256 < Sb;                // state 256 exists iff tl == 128

  __shared__ float A[2][264];                  // A[p][2+state]; slots 0,1 = NEG pads
  if (s < 2) { A[0][s] = NEGV; A[1][s] = NEGV; }

  float a  = (s < 2) ? base[s] : NEGV;         // t=0: only states 0,1 alive
  float a2 = NEGV;                             // alpha[256] (thread 255's copy)
  A[0][2 + s] = a;
  if (last) A[0][2 + 256] = a2;
  __syncthreads();

  constexpr int PD = 8;
  float ring[PD], ringx[PD];
#pragma unroll
  for (int d = 0; d < PD; ++d) {
    int idx = 1 + d; if (idx >= len) idx = len - 1;
    const float* r = base + (size_t)idx * SSTRIDE;
    ring[d]  = r[s];
    ringx[d] = r[256];                         // wave-uniform address -> scalar load
  }

  int p = 0;
  auto body = [&](float g, float gx) {
    float am1 = A[p][s + 1];                   // alpha[s-1]   (2+s-1)
    float am2 = A[p][s];                       // alpha[s-2]   (2+s-2)
    float q2 = sk ? am2 : NEGV;
    float m = fmaxf(a, fmaxf(am1, q2));
    float sum = __builtin_amdgcn_exp2f(a - m) + __builtin_amdgcn_exp2f(am1 - m) +
                __builtin_amdgcn_exp2f(q2 - m);
    float n = g + m + __builtin_amdgcn_logf(sum);
    n = valid ? n : NEGV;
    // state 256 (blank, even): LSE(alpha[256], alpha[255]) -- uses OLD a
    float m2 = fmaxf(a2, a);
    float n2 = gx + m2 + __builtin_amdgcn_logf(__builtin_amdgcn_exp2f(a2 - m2) +
                                               __builtin_amdgcn_exp2f(a - m2));
    n2 = valid2 ? n2 : NEGV;
    a = n;
    a2 = n2;
    A[p ^ 1][2 + s] = a;
    if (last) A[p ^ 1][2 + 256] = a2;
    __syncthreads();
    p ^= 1;
  };

  int t = 1;
  for (; t + PD - 1 < len; t += PD) {
#pragma unroll
    for (int d = 0; d < PD; ++d) {
      float g = ring[d], gx = ringx[d];
      int idx = t + d + PD; if (idx >= len) idx = len - 1;  // clamped rows never consumed
      const float* r = base + (size_t)idx * SSTRIDE;
      ring[d]  = r[s];
      ringx[d] = r[256];
      body(g, gx);
    }
  }
  for (int d = 0; t < len; ++t, ++d) body(ring[d], ringx[d]);

  // epilogue
  A[p][2 + s] = a;
  if (last) A[p][2 + 256] = a2;
  __syncthreads();
  if (s == 0) {
    float x = A[p][2 + Sb - 1];
    float y = A[p][2 + Sb - 2];
    float m = fmaxf(x, y);
    float llh2 = m + __builtin_amdgcn_logf(__builtin_amdgcn_exp2f(x - m) +
                                           __builtin_amdgcn_exp2f(y - m));
    out[b] = -llh2 * LN2;                      // normalizer ~ 0 (input is log-softmax)
  }
}

extern "C" void kernel_launch(void* const* d_in, const int* in_sizes, int n_in,
                              void* d_out, int out_size, void* d_ws, size_t ws_size,
                              hipStream_t stream) {
  const float* lp = (const float*)d_in[0];
  const int* targets = (const int*)d_in[1];
  const int* ilen = (const int*)d_in[2];
  const int* tlen = (const int*)d_in[3];
  float* out = (float*)d_out;

  const int B = in_sizes[2];                 // 32
  const int L = in_sizes[1] / B;             // 128
  const int C = 1024;                        // per reference
  const int T = in_sizes[0] / (B * C);       // 1600

  float* em = (float*)d_ws;                  // B*T*SSTRIDE fp32 = ~54 MB

  const int rows = B * T;
  gather_kernel<<<(rows + 3) / 4, 256, 0, stream>>>(lp, targets, ilen, tlen, em, B, T, C, L);
  ctc_dp_kernel<<<B, 256, 0, stream>>>(em, targets, ilen, tlen, out, T, L);
}